// Round 11
// baseline (405.570 us; speedup 1.0000x reference)
//
#include <hip/hip_runtime.h>
#include <hip/hip_bf16.h>
#include <math.h>

// Problem constants (match reference)
#define BB  32
#define SS  4096
#define VV  256
#define DD  256
#define CC  2
#define WIN 64
#define NW  64   // SS/WIN

typedef unsigned short ushort_t;
typedef unsigned int   uint_t;
typedef __attribute__((ext_vector_type(8))) short short8;    // 8 bf16 (4 VGPRs)
typedef __attribute__((ext_vector_type(4))) float f32x4;

// Workspace layout (byte offsets).
#define WS_ATHI_B 0u          // ushort Athi[64][64]   8192  (A-op layout: [t][s])
#define WS_ATLO_B 8192u       // ushort Atlo[64][64]   8192
#define WS_GPK_B  16384u      // uint   gpk[256][256]  262144 (hi<<16 | lo per elem)
#define WS_W2HI_B 278528u     // ushort W2hi[256][256] 131072
#define WS_W2LO_B 409600u     // ushort W2lo[256][256] 131072

#define HP 264    // H2 plane row stride in shorts (256 + 8 pad)

__device__ __forceinline__ float fast_tanh(float v) {
  float e = __expf(2.0f * v);
  return 1.0f - __fdividef(2.0f, e + 1.0f);
}

// Truncation-based bf16 split: v ~= hi + lo with |err| <= 2^-17 * |v|.
__device__ __forceinline__ uint_t split_pack(float v) {
  uint_t b  = __float_as_uint(v);
  uint_t hi = b & 0xffff0000u;
  float  r  = v - __uint_as_float(hi);
  uint_t lo = __float_as_uint(r) >> 16;
  return hi | lo;
}

// Pack hi/lo halves of two packed u32 into bf16 pair dwords via v_perm.
__device__ __forceinline__ uint_t perm_hi(uint_t p0, uint_t p1) {
  return __builtin_amdgcn_perm(p1, p0, 0x07060302u);
}
__device__ __forceinline__ uint_t perm_lo(uint_t p0, uint_t p1) {
  return __builtin_amdgcn_perm(p1, p0, 0x05040100u);
}

union u4s8 { uint_t u[4]; short8 v; };

// ---------------------------------------------------------------------------
// Prep grid (1090 blocks):
//  blk 0          : attention matrix -> split bf16 planes Athi/Atlo ([t][s])
//  blk 1          : out[b][c] = bc[c]  (main atomically accumulates into out)
//  blk 2..1025    : g = emb @ W1^T (coalesced W1 reads, LDS partial reduce)
//  blk 1026..1089 : W2 -> split planes W2hi/W2lo, 4 c-rows per block
// ---------------------------------------------------------------------------
__global__ __launch_bounds__(256) void prep_kernel(
    const float* __restrict__ emb, const float* __restrict__ W1,
    const float* __restrict__ W2,  const float* __restrict__ bc,
    float* __restrict__ out, char* __restrict__ ws)
{
  const int blk = blockIdx.x;
  const int tid = threadIdx.x;
  ushort_t* Athi = (ushort_t*)(ws + WS_ATHI_B);
  ushort_t* Atlo = (ushort_t*)(ws + WS_ATLO_B);
  uint_t*   gpk  = (uint_t*)  (ws + WS_GPK_B);
  ushort_t* W2hi = (ushort_t*)(ws + WS_W2HI_B);
  ushort_t* W2lo = (ushort_t*)(ws + WS_W2LO_B);

  if (blk == 0) {
    if (tid < WIN) {
      const int s = tid;
      const float omega = 60.0f * 2.0f * 3.14159265358979323846f / 4095.0f;
      float row[WIN];
      float sum = 0.0f;
      for (int t = 0; t < WIN; ++t) {
        float e = expf(cosf(omega * (float)(s - t)));
        row[t] = e;
        sum += e;
      }
      const float inv = 1.0f / sum;
      for (int t = 0; t < WIN; ++t) {
        uint_t pk = split_pack(row[t] * inv);
        Athi[t * WIN + s] = (ushort_t)(pk >> 16);
        Atlo[t * WIN + s] = (ushort_t)(pk & 0xffffu);
      }
    }
  } else if (blk == 1) {
    if (tid < BB * CC) out[tid] = bc[tid & 1];
  } else if (blk < 1026) {
    const int gv = blk - 2;            // 0..1023
    const int d0 = (gv & 15) * 16;     // 16 d-columns
    const int v0 = (gv >> 4) * 4;      // 4 v-rows
    __shared__ float er[4 * DD];       // 4 KB
    __shared__ float ps[4][16][17];    // padded partials
    *(float4*)(er + tid * 4) = *(const float4*)(emb + v0 * DD + tid * 4);
    __syncthreads();
    const int kq = tid & 15;           // k-strip: [16kq, 16kq+16)
    const int dl = tid >> 4;           // 0..15
    const int d  = d0 + dl;
    float4 wv[4];
    #pragma unroll
    for (int j = 0; j < 4; ++j)
      wv[j] = *(const float4*)(W1 + d * DD + 16 * kq + 4 * j);  // coalesced
    #pragma unroll
    for (int v = 0; v < 4; ++v) {
      float a = 0.0f;
      #pragma unroll
      for (int j = 0; j < 4; ++j) {
        float4 e = *(const float4*)(er + v * DD + 16 * kq + 4 * j);
        a += e.x * wv[j].x + e.y * wv[j].y + e.z * wv[j].z + e.w * wv[j].w;
      }
      ps[v][dl][kq] = a;
    }
    __syncthreads();
    if (tid < 64) {
      const int v = tid >> 4, dr = tid & 15;
      float s = 0.0f;
      #pragma unroll
      for (int k = 0; k < 16; ++k) s += ps[v][dr][k];
      gpk[(v0 + v) * DD + d0 + dr] = split_pack(s);
    }
  } else {
    const int c0 = (blk - 1026) * 4;
    #pragma unroll
    for (int i = 0; i < 4; ++i) {
      const int c = c0 + i;
      uint_t pk = split_pack(W2[c * DD + tid]);
      W2hi[c * DD + tid] = (ushort_t)(pk >> 16);
      W2lo[c * DD + tid] = (ushort_t)(pk & 0xffffu);
    }
  }
}

// ---------------------------------------------------------------------------
// Main fused kernel: one block (512 thr, 8 waves) per (batch b, window n).
// R8 skeleton (proven spill-free, 2 blocks/CU) + micro-fixes:
//  (1) gather tokens re-read per-quad from x (L1 broadcast) — NO ds_bpermute
//      (the bpermutes were ~1K LDS-crossbar cyc/window, SQ_LDS_BANK_CONFLICT).
//  (2) MFMA de-chained: product-outer order; P4 interleaves mt-pairs ->
//      same-accumulator spacing 2-4 instructions instead of 0.
//  (3) linear head fused: pacc folded into Wc, 2 atomicAdds/wave into out.
// ---------------------------------------------------------------------------
__global__ __launch_bounds__(512, 4) void main_kernel(
    const int*      __restrict__ x,    const uint_t* __restrict__ gpk,
    const ushort_t* __restrict__ Athi, const ushort_t* __restrict__ Atlo,
    const float*    __restrict__ b1,
    const ushort_t* __restrict__ W2hi, const ushort_t* __restrict__ W2lo,
    const float*    __restrict__ b2,   const float* __restrict__ Wc,
    float* __restrict__ out)
{
  __shared__ ushort_t Hhi[WIN][HP];   // 33792 B
  __shared__ ushort_t Hlo[WIN][HP];   // 33792 B (total 67584 -> 2 blocks/CU)

  const int tid  = threadIdx.x;
  const int lane = tid & 63;
  const int w    = tid >> 6;       // 0..7
  const int quad = lane >> 4;
  const int l16  = lane & 15;
  const int b = blockIdx.x >> 6;
  const int n = blockIdx.x & 63;

  const int dbase = 32 * w;        // this wave's d-slice (P2) == c-slice (P4)
  const int cbase = dbase;

  // --- P1: gather. Token ids read per-quad (uniform within quad -> L1
  // broadcast), gather loads issued immediately (latency overlaps setup).
  const int sbase = b * SS + n * WIN;
  uint_t q[2][2][8];
  #pragma unroll
  for (int k0 = 0; k0 < 2; ++k0) {
    const int sl = k0 * 32 + quad * 8;
    int tb[8];
    #pragma unroll
    for (int j = 0; j < 8; ++j) tb[j] = x[sbase + sl + j];   // quad-uniform
    #pragma unroll
    for (int nt = 0; nt < 2; ++nt) {
      const int d = dbase + 16 * nt + l16;
      #pragma unroll
      for (int j = 0; j < 8; ++j) q[k0][nt][j] = gpk[tb[j] * DD + d];
    }
  }

  float b1v[2], b2v[2];
  #pragma unroll
  for (int nt = 0; nt < 2; ++nt) {
    b1v[nt] = b1[dbase + 16 * nt + l16];
    b2v[nt] = b2[cbase + 16 * nt + l16];
  }

  // --- P2: attention MFMA (product-outer within mt: spacing 2) ---
  f32x4 acc1[4][2];
  #pragma unroll
  for (int mt = 0; mt < 4; ++mt)
    #pragma unroll
    for (int nt = 0; nt < 2; ++nt) acc1[mt][nt] = (f32x4)0.0f;

  #pragma unroll
  for (int k0 = 0; k0 < 2; ++k0) {
    const int sl = k0 * 32 + quad * 8;
    short8 bh[2], bl[2];
    #pragma unroll
    for (int nt = 0; nt < 2; ++nt) {
      u4s8 h, l;
      #pragma unroll
      for (int p = 0; p < 4; ++p) {
        h.u[p] = perm_hi(q[k0][nt][2 * p], q[k0][nt][2 * p + 1]);
        l.u[p] = perm_lo(q[k0][nt][2 * p], q[k0][nt][2 * p + 1]);
      }
      bh[nt] = h.v;
      bl[nt] = l.v;
    }
    #pragma unroll
    for (int mt = 0; mt < 4; ++mt) {
      const int t = mt * 16 + l16;
      short8 ah = *(const short8*)(Athi + t * WIN + sl);   // L1/L2
      short8 al = *(const short8*)(Atlo + t * WIN + sl);
      acc1[mt][0] = __builtin_amdgcn_mfma_f32_16x16x32_bf16(ah, bh[0], acc1[mt][0], 0, 0, 0);
      acc1[mt][1] = __builtin_amdgcn_mfma_f32_16x16x32_bf16(ah, bh[1], acc1[mt][1], 0, 0, 0);
      acc1[mt][0] = __builtin_amdgcn_mfma_f32_16x16x32_bf16(ah, bl[0], acc1[mt][0], 0, 0, 0);
      acc1[mt][1] = __builtin_amdgcn_mfma_f32_16x16x32_bf16(ah, bl[1], acc1[mt][1], 0, 0, 0);
      acc1[mt][0] = __builtin_amdgcn_mfma_f32_16x16x32_bf16(al, bh[0], acc1[mt][0], 0, 0, 0);
      acc1[mt][1] = __builtin_amdgcn_mfma_f32_16x16x32_bf16(al, bh[1], acc1[mt][1], 0, 0, 0);
    }
  }

  // --- P3: tanh(+b1), split, store to hi/lo planes (2-addr/bank = free) ---
  #pragma unroll
  for (int nt = 0; nt < 2; ++nt) {
    const int d = dbase + 16 * nt + l16;
    #pragma unroll
    for (int mt = 0; mt < 4; ++mt)
      #pragma unroll
      for (int r = 0; r < 4; ++r) {
        const int t = mt * 16 + quad * 4 + r;
        float h = fast_tanh(acc1[mt][nt][r] + b1v[nt]);
        uint_t pk = split_pack(h);
        Hhi[t][d] = (ushort_t)(pk >> 16);
        Hlo[t][d] = (ushort_t)(pk & 0xffffu);
      }
  }
  __syncthreads();   // the only barrier

  // --- P4: matmul2 MFMA, W2 double-buffered, mt-pair interleave (spacing 4) ---
  f32x4 acc2[4][2];
  #pragma unroll
  for (int mt = 0; mt < 4; ++mt)
    #pragma unroll
    for (int nt = 0; nt < 2; ++nt) acc2[mt][nt] = (f32x4)0.0f;

  short8 wh[2][2], wl[2][2];
  {
    const int dsl0 = quad * 8;
    #pragma unroll
    for (int nt = 0; nt < 2; ++nt) {
      const int c = cbase + 16 * nt + l16;
      wh[0][nt] = *(const short8*)(W2hi + c * DD + dsl0);
      wl[0][nt] = *(const short8*)(W2lo + c * DD + dsl0);
    }
  }

  #pragma unroll 2
  for (int k0 = 0; k0 < 8; ++k0) {
    const int cur = k0 & 1, nxt = cur ^ 1;
    const int dsl = k0 * 32 + quad * 8;
    if (k0 < 7) {
      const int dsln = dsl + 32;
      #pragma unroll
      for (int nt = 0; nt < 2; ++nt) {
        const int c = cbase + 16 * nt + l16;
        wh[nxt][nt] = *(const short8*)(W2hi + c * DD + dsln);   // prefetch k0+1
        wl[nxt][nt] = *(const short8*)(W2lo + c * DD + dsln);
      }
    }
    #pragma unroll
    for (int mp = 0; mp < 2; ++mp) {
      const int m0 = 2 * mp, m1 = 2 * mp + 1;
      const int t0 = m0 * 16 + l16, t1 = m1 * 16 + l16;
      short8 ah0 = *(const short8*)(&Hhi[t0][dsl]);   // ds_read_b128, clean
      short8 al0 = *(const short8*)(&Hlo[t0][dsl]);
      short8 ah1 = *(const short8*)(&Hhi[t1][dsl]);
      short8 al1 = *(const short8*)(&Hlo[t1][dsl]);
      // product-outer, m-interleaved: same-acc spacing = 4 instructions
      acc2[m0][0] = __builtin_amdgcn_mfma_f32_16x16x32_bf16(ah0, wh[cur][0], acc2[m0][0], 0, 0, 0);
      acc2[m0][1] = __builtin_amdgcn_mfma_f32_16x16x32_bf16(ah0, wh[cur][1], acc2[m0][1], 0, 0, 0);
      acc2[m1][0] = __builtin_amdgcn_mfma_f32_16x16x32_bf16(ah1, wh[cur][0], acc2[m1][0], 0, 0, 0);
      acc2[m1][1] = __builtin_amdgcn_mfma_f32_16x16x32_bf16(ah1, wh[cur][1], acc2[m1][1], 0, 0, 0);
      acc2[m0][0] = __builtin_amdgcn_mfma_f32_16x16x32_bf16(ah0, wl[cur][0], acc2[m0][0], 0, 0, 0);
      acc2[m0][1] = __builtin_amdgcn_mfma_f32_16x16x32_bf16(ah0, wl[cur][1], acc2[m0][1], 0, 0, 0);
      acc2[m1][0] = __builtin_amdgcn_mfma_f32_16x16x32_bf16(ah1, wl[cur][0], acc2[m1][0], 0, 0, 0);
      acc2[m1][1] = __builtin_amdgcn_mfma_f32_16x16x32_bf16(ah1, wl[cur][1], acc2[m1][1], 0, 0, 0);
      acc2[m0][0] = __builtin_amdgcn_mfma_f32_16x16x32_bf16(al0, wh[cur][0], acc2[m0][0], 0, 0, 0);
      acc2[m0][1] = __builtin_amdgcn_mfma_f32_16x16x32_bf16(al0, wh[cur][1], acc2[m0][1], 0, 0, 0);
      acc2[m1][0] = __builtin_amdgcn_mfma_f32_16x16x32_bf16(al1, wh[cur][0], acc2[m1][0], 0, 0, 0);
      acc2[m1][1] = __builtin_amdgcn_mfma_f32_16x16x32_bf16(al1, wh[cur][1], acc2[m1][1], 0, 0, 0);
    }
  }

  // --- P5: tanh(+b2), token-sum, fold into Wc (linear head), atomics ---
  float pacc[2];
  #pragma unroll
  for (int nt = 0; nt < 2; ++nt) {
    float p = 0.0f;
    #pragma unroll
    for (int mt = 0; mt < 4; ++mt)
      #pragma unroll
      for (int r = 0; r < 4; ++r)
        p += fast_tanh(acc2[mt][nt][r] + b2v[nt]);
    p += __shfl_xor(p, 16, 64);   // sum across quads (different t only)
    p += __shfl_xor(p, 32, 64);
    pacc[nt] = p;                 // token-sum for c = cbase + 16*nt + l16
  }
  float s0 = pacc[0] * Wc[cbase + l16]      + pacc[1] * Wc[cbase + 16 + l16];
  float s1 = pacc[0] * Wc[DD + cbase + l16] + pacc[1] * Wc[DD + cbase + 16 + l16];
  #pragma unroll
  for (int off = 1; off < 16; off <<= 1) {   // reduce over l16 (quads identical)
    s0 += __shfl_xor(s0, off, 64);
    s1 += __shfl_xor(s1, off, 64);
  }
  if (lane == 0) {
    atomicAdd(&out[b * CC + 0], s0 * (1.0f / SS));
    atomicAdd(&out[b * CC + 1], s1 * (1.0f / SS));
  }
}

extern "C" void kernel_launch(void* const* d_in, const int* in_sizes, int n_in,
                              void* d_out, int out_size, void* d_ws, size_t ws_size,
                              hipStream_t stream) {
  const int*   x   = (const int*)  d_in[0];
  const float* emb = (const float*)d_in[1];
  const float* W1  = (const float*)d_in[2];
  const float* b1  = (const float*)d_in[3];
  const float* W2  = (const float*)d_in[4];
  const float* b2  = (const float*)d_in[5];
  const float* Wc  = (const float*)d_in[6];
  const float* bc  = (const float*)d_in[7];
  float* out = (float*)d_out;
  char*  ws  = (char*)d_ws;

  prep_kernel<<<1090, 256, 0, stream>>>(emb, W1, W2, bc, out, ws);
  main_kernel<<<BB * NW, 512, 0, stream>>>(
      x,
      (const uint_t*)  (ws + WS_GPK_B),
      (const ushort_t*)(ws + WS_ATHI_B), (const ushort_t*)(ws + WS_ATLO_B),
      b1,
      (const ushort_t*)(ws + WS_W2HI_B), (const ushort_t*)(ws + WS_W2LO_B),
      b2, Wc, out);
}

// Round 12
// 370.785 us; speedup vs baseline: 1.0938x; 1.0938x over previous
//
#include <hip/hip_runtime.h>
#include <hip/hip_bf16.h>
#include <math.h>

// Problem constants (match reference)
#define BB  32
#define SS  4096
#define VV  256
#define DD  256
#define CC  2
#define WIN 64
#define NW  64   // SS/WIN

typedef unsigned short ushort_t;
typedef unsigned int   uint_t;
typedef __attribute__((ext_vector_type(8))) short short8;    // 8 bf16 (4 VGPRs)
typedef __attribute__((ext_vector_type(4))) float f32x4;

// Workspace layout (byte offsets).
#define WS_ATHI_B 0u          // ushort Athi[64][64]   8192  (A-op layout: [t][s])
#define WS_ATLO_B 8192u       // ushort Atlo[64][64]   8192
#define WS_GPK_B  16384u      // uint   gpk[256][256]  262144 (hi<<16 | lo per elem)
#define WS_W2HI_B 278528u     // ushort W2hi[256][256] 131072
#define WS_W2LO_B 409600u     // ushort W2lo[256][256] 131072

__device__ __forceinline__ float fast_tanh(float v) {
  float e = __expf(2.0f * v);
  return 1.0f - __fdividef(2.0f, e + 1.0f);
}

// Truncation-based bf16 split: v ~= hi + lo with |err| <= 2^-17 * |v|.
__device__ __forceinline__ uint_t split_pack(float v) {
  uint_t b  = __float_as_uint(v);
  uint_t hi = b & 0xffff0000u;
  float  r  = v - __uint_as_float(hi);
  uint_t lo = __float_as_uint(r) >> 16;
  return hi | lo;
}

// Pack hi/lo halves of two packed u32 into bf16 pair dwords via v_perm.
__device__ __forceinline__ uint_t perm_hi(uint_t p0, uint_t p1) {
  return __builtin_amdgcn_perm(p1, p0, 0x07060302u);
}
__device__ __forceinline__ uint_t perm_lo(uint_t p0, uint_t p1) {
  return __builtin_amdgcn_perm(p1, p0, 0x05040100u);
}

union u4s8 { uint_t u[4]; short8 v; };

// ---------------------------------------------------------------------------
// Prep grid (1090 blocks):
//  blk 0          : attention matrix -> split bf16 planes Athi/Atlo ([t][s])
//  blk 1          : out[b][c] = bc[c]  (main atomically accumulates into out)
//  blk 2..1025    : g = emb @ W1^T (coalesced W1 reads, LDS partial reduce)
//  blk 1026..1089 : W2 -> split planes W2hi/W2lo, 4 c-rows per block
// ---------------------------------------------------------------------------
__global__ __launch_bounds__(256) void prep_kernel(
    const float* __restrict__ emb, const float* __restrict__ W1,
    const float* __restrict__ W2,  const float* __restrict__ bc,
    float* __restrict__ out, char* __restrict__ ws)
{
  const int blk = blockIdx.x;
  const int tid = threadIdx.x;
  ushort_t* Athi = (ushort_t*)(ws + WS_ATHI_B);
  ushort_t* Atlo = (ushort_t*)(ws + WS_ATLO_B);
  uint_t*   gpk  = (uint_t*)  (ws + WS_GPK_B);
  ushort_t* W2hi = (ushort_t*)(ws + WS_W2HI_B);
  ushort_t* W2lo = (ushort_t*)(ws + WS_W2LO_B);

  if (blk == 0) {
    if (tid < WIN) {
      const int s = tid;
      const float omega = 60.0f * 2.0f * 3.14159265358979323846f / 4095.0f;
      float row[WIN];
      float sum = 0.0f;
      for (int t = 0; t < WIN; ++t) {
        float e = expf(cosf(omega * (float)(s - t)));
        row[t] = e;
        sum += e;
      }
      const float inv = 1.0f / sum;
      for (int t = 0; t < WIN; ++t) {
        uint_t pk = split_pack(row[t] * inv);
        Athi[t * WIN + s] = (ushort_t)(pk >> 16);
        Atlo[t * WIN + s] = (ushort_t)(pk & 0xffffu);
      }
    }
  } else if (blk == 1) {
    if (tid < BB * CC) out[tid] = bc[tid & 1];
  } else if (blk < 1026) {
    const int gv = blk - 2;            // 0..1023
    const int d0 = (gv & 15) * 16;     // 16 d-columns
    const int v0 = (gv >> 4) * 4;      // 4 v-rows
    __shared__ float er[4 * DD];       // 4 KB
    __shared__ float ps[4][16][17];    // padded partials
    *(float4*)(er + tid * 4) = *(const float4*)(emb + v0 * DD + tid * 4);
    __syncthreads();
    const int kq = tid & 15;           // k-strip: [16kq, 16kq+16)
    const int dl = tid >> 4;           // 0..15
    const int d  = d0 + dl;
    float4 wv[4];
    #pragma unroll
    for (int j = 0; j < 4; ++j)
      wv[j] = *(const float4*)(W1 + d * DD + 16 * kq + 4 * j);  // coalesced
    #pragma unroll
    for (int v = 0; v < 4; ++v) {
      float a = 0.0f;
      #pragma unroll
      for (int j = 0; j < 4; ++j) {
        float4 e = *(const float4*)(er + v * DD + 16 * kq + 4 * j);
        a += e.x * wv[j].x + e.y * wv[j].y + e.z * wv[j].z + e.w * wv[j].w;
      }
      ps[v][dl][kq] = a;
    }
    __syncthreads();
    if (tid < 64) {
      const int v = tid >> 4, dr = tid & 15;
      float s = 0.0f;
      #pragma unroll
      for (int k = 0; k < 16; ++k) s += ps[v][dr][k];
      gpk[(v0 + v) * DD + d0 + dr] = split_pack(s);
    }
  } else {
    const int c0 = (blk - 1026) * 4;
    #pragma unroll
    for (int i = 0; i < 4; ++i) {
      const int c = c0 + i;
      uint_t pk = split_pack(W2[c * DD + tid]);
      W2hi[c * DD + tid] = (ushort_t)(pk >> 16);
      W2lo[c * DD + tid] = (ushort_t)(pk & 0xffffu);
    }
  }
}

// ---------------------------------------------------------------------------
// Main fused kernel: one block (512 thr, 8 waves) per (batch b, window n).
// R8 skeleton (proven 122 us, spill-free) + this round's deltas:
//  (1) amdgpu_waves_per_eu(4,4): LDS caps us at 2 blocks/CU = 4 waves/EU
//      anyway; stop the allocator from squeezing to 64 VGPR for unreachable
//      8-wave occupancy. 128-VGPR budget keeps gather/W2 loads in flight.
//  (2) H2 chunk-rotation swizzle col=(((d>>3)+t)&31)*8+(d&7), stride 256:
//      P3 writes -> 2 accesses/bank (free, m136); P4 b128 reads -> exact
//      8-phase minimum (bank arithmetic both sides). No pad; LDS 64 KB.
//  (3) W2 slot-0 preload issued pre-barrier (completes under barrier drain).
//  (4) fused linear head (R10-proven): no pool buffer, no final kernel.
// ---------------------------------------------------------------------------
__global__ __launch_bounds__(512)
__attribute__((amdgpu_waves_per_eu(4, 4)))
void main_kernel(
    const int*      __restrict__ x,    const uint_t* __restrict__ gpk,
    const ushort_t* __restrict__ Athi, const ushort_t* __restrict__ Atlo,
    const float*    __restrict__ b1,
    const ushort_t* __restrict__ W2hi, const ushort_t* __restrict__ W2lo,
    const float*    __restrict__ b2,   const float* __restrict__ Wc,
    float* __restrict__ out)
{
  __shared__ ushort_t Hhi[WIN][DD];   // 32 KB, swizzled columns
  __shared__ ushort_t Hlo[WIN][DD];   // 32 KB (total 64 KB -> 2 blocks/CU)

  const int tid  = threadIdx.x;
  const int lane = tid & 63;
  const int w    = tid >> 6;       // 0..7
  const int quad = lane >> 4;
  const int l16  = lane & 15;
  const int b = blockIdx.x >> 6;
  const int n = blockIdx.x & 63;

  const int dbase = 32 * w;        // this wave's d-slice (P2) == c-slice (P4)
  const int cbase = dbase;

  // --- P1: gather (single x load + shfl broadcast — R8 pattern) ---
  const int xv = x[b * SS + n * WIN + lane];
  uint_t q[2][2][8];
  #pragma unroll
  for (int k0 = 0; k0 < 2; ++k0) {
    const int sl = k0 * 32 + quad * 8;
    int xs[8];
    #pragma unroll
    for (int j = 0; j < 8; ++j) xs[j] = __shfl(xv, sl + j, 64);
    #pragma unroll
    for (int nt = 0; nt < 2; ++nt) {
      const int d = dbase + 16 * nt + l16;
      #pragma unroll
      for (int j = 0; j < 8; ++j) q[k0][nt][j] = gpk[xs[j] * DD + d];
    }
  }

  // --- early W2 slot-0 preload: independent of H2, completes by the barrier
  short8 wh[2][2], wl[2][2];
  {
    const int dsl0 = quad * 8;
    #pragma unroll
    for (int nt = 0; nt < 2; ++nt) {
      const int c = cbase + 16 * nt + l16;
      wh[0][nt] = *(const short8*)(W2hi + c * DD + dsl0);
      wl[0][nt] = *(const short8*)(W2lo + c * DD + dsl0);
    }
  }

  float b1v[2], b2v[2];
  #pragma unroll
  for (int nt = 0; nt < 2; ++nt) {
    b1v[nt] = b1[dbase + 16 * nt + l16];
    b2v[nt] = b2[cbase + 16 * nt + l16];
  }

  // --- P2: attention MFMA (R8 ordering) ---
  f32x4 acc1[4][2];
  #pragma unroll
  for (int mt = 0; mt < 4; ++mt)
    #pragma unroll
    for (int nt = 0; nt < 2; ++nt) acc1[mt][nt] = (f32x4)0.0f;

  #pragma unroll
  for (int k0 = 0; k0 < 2; ++k0) {
    const int sl = k0 * 32 + quad * 8;
    short8 bh[2], bl[2];
    #pragma unroll
    for (int nt = 0; nt < 2; ++nt) {
      u4s8 h, l;
      #pragma unroll
      for (int p = 0; p < 4; ++p) {
        h.u[p] = perm_hi(q[k0][nt][2 * p], q[k0][nt][2 * p + 1]);
        l.u[p] = perm_lo(q[k0][nt][2 * p], q[k0][nt][2 * p + 1]);
      }
      bh[nt] = h.v;
      bl[nt] = l.v;
    }
    #pragma unroll
    for (int mt = 0; mt < 4; ++mt) {
      const int t = mt * 16 + l16;
      short8 ah = *(const short8*)(Athi + t * WIN + sl);   // L1/L2-resident
      short8 al = *(const short8*)(Atlo + t * WIN + sl);
      #pragma unroll
      for (int nt = 0; nt < 2; ++nt) {
        acc1[mt][nt] = __builtin_amdgcn_mfma_f32_16x16x32_bf16(ah, bh[nt], acc1[mt][nt], 0, 0, 0);
        acc1[mt][nt] = __builtin_amdgcn_mfma_f32_16x16x32_bf16(ah, bl[nt], acc1[mt][nt], 0, 0, 0);
        acc1[mt][nt] = __builtin_amdgcn_mfma_f32_16x16x32_bf16(al, bh[nt], acc1[mt][nt], 0, 0, 0);
      }
    }
  }

  // --- P3: tanh(+b1), split, swizzled store (2 accesses/bank = free) ---
  #pragma unroll
  for (int nt = 0; nt < 2; ++nt) {
    const int d = dbase + 16 * nt + l16;
    #pragma unroll
    for (int mt = 0; mt < 4; ++mt)
      #pragma unroll
      for (int r = 0; r < 4; ++r) {
        const int t = mt * 16 + quad * 4 + r;
        float h = fast_tanh(acc1[mt][nt][r] + b1v[nt]);
        uint_t pk = split_pack(h);
        const int col = ((((d >> 3) + t) & 31) << 3) + (d & 7);
        Hhi[t][col] = (ushort_t)(pk >> 16);
        Hlo[t][col] = (ushort_t)(pk & 0xffffu);
      }
  }
  __syncthreads();   // the only barrier

  // --- P4: matmul2 MFMA, W2 double-buffered (slot 0 already resident) ---
  f32x4 acc2[4][2];
  #pragma unroll
  for (int mt = 0; mt < 4; ++mt)
    #pragma unroll
    for (int nt = 0; nt < 2; ++nt) acc2[mt][nt] = (f32x4)0.0f;

  #pragma unroll 2
  for (int k0 = 0; k0 < 8; ++k0) {
    const int cur = k0 & 1, nxt = cur ^ 1;
    const int dsl = k0 * 32 + quad * 8;
    if (k0 < 7) {
      const int dsln = dsl + 32;
      #pragma unroll
      for (int nt = 0; nt < 2; ++nt) {
        const int c = cbase + 16 * nt + l16;
        wh[nxt][nt] = *(const short8*)(W2hi + c * DD + dsln);   // prefetch k0+1
        wl[nxt][nt] = *(const short8*)(W2lo + c * DD + dsln);
      }
    }
    const int ch0 = 4 * k0 + quad;       // chunk base for this lane's k-slice
    #pragma unroll
    for (int mt = 0; mt < 4; ++mt) {
      const int t = mt * 16 + l16;
      const int col = ((ch0 + t) & 31) << 3;
      short8 ah = *(const short8*)(&Hhi[t][col]);   // ds_read_b128, 8-phase min
      short8 al = *(const short8*)(&Hlo[t][col]);
      #pragma unroll
      for (int nt = 0; nt < 2; ++nt) {
        acc2[mt][nt] = __builtin_amdgcn_mfma_f32_16x16x32_bf16(ah, wh[cur][nt], acc2[mt][nt], 0, 0, 0);
        acc2[mt][nt] = __builtin_amdgcn_mfma_f32_16x16x32_bf16(ah, wl[cur][nt], acc2[mt][nt], 0, 0, 0);
        acc2[mt][nt] = __builtin_amdgcn_mfma_f32_16x16x32_bf16(al, wh[cur][nt], acc2[mt][nt], 0, 0, 0);
      }
    }
  }

  // --- P5: tanh(+b2), token-sum, fold into Wc (linear head), atomics ---
  float pacc[2];
  #pragma unroll
  for (int nt = 0; nt < 2; ++nt) {
    float p = 0.0f;
    #pragma unroll
    for (int mt = 0; mt < 4; ++mt)
      #pragma unroll
      for (int r = 0; r < 4; ++r)
        p += fast_tanh(acc2[mt][nt][r] + b2v[nt]);
    p += __shfl_xor(p, 16, 64);   // sum across quads (different t only)
    p += __shfl_xor(p, 32, 64);
    pacc[nt] = p;                 // token-sum for c = cbase + 16*nt + l16
  }
  float s0 = pacc[0] * Wc[cbase + l16]      + pacc[1] * Wc[cbase + 16 + l16];
  float s1 = pacc[0] * Wc[DD + cbase + l16] + pacc[1] * Wc[DD + cbase + 16 + l16];
  #pragma unroll
  for (int off = 1; off < 16; off <<= 1) {   // reduce over l16 (quads identical)
    s0 += __shfl_xor(s0, off, 64);
    s1 += __shfl_xor(s1, off, 64);
  }
  if (lane == 0) {
    atomicAdd(&out[b * CC + 0], s0 * (1.0f / SS));
    atomicAdd(&out[b * CC + 1], s1 * (1.0f / SS));
  }
}

extern "C" void kernel_launch(void* const* d_in, const int* in_sizes, int n_in,
                              void* d_out, int out_size, void* d_ws, size_t ws_size,
                              hipStream_t stream) {
  const int*   x   = (const int*)  d_in[0];
  const float* emb = (const float*)d_in[1];
  const float* W1  = (const float*)d_in[2];
  const float* b1  = (const float*)d_in[3];
  const float* W2  = (const float*)d_in[4];
  const float* b2  = (const float*)d_in[5];
  const float* Wc  = (const float*)d_in[6];
  const float* bc  = (const float*)d_in[7];
  float* out = (float*)d_out;
  char*  ws  = (char*)d_ws;

  prep_kernel<<<1090, 256, 0, stream>>>(emb, W1, W2, bc, out, ws);
  main_kernel<<<BB * NW, 512, 0, stream>>>(
      x,
      (const uint_t*)  (ws + WS_GPK_B),
      (const ushort_t*)(ws + WS_ATHI_B), (const ushort_t*)(ws + WS_ATLO_B),
      b1,
      (const ushort_t*)(ws + WS_W2HI_B), (const ushort_t*)(ws + WS_W2LO_B),
      b2, Wc, out);
}

// Round 13
// 201.982 us; speedup vs baseline: 2.0080x; 1.8357x over previous
//
#include <hip/hip_runtime.h>
#include <hip/hip_bf16.h>
#include <math.h>

// Problem constants (match reference)
#define BB  32
#define SS  4096
#define VV  256
#define DD  256
#define CC  2
#define WIN 64
#define NW  64   // SS/WIN

typedef unsigned short ushort_t;
typedef unsigned int   uint_t;
typedef __attribute__((ext_vector_type(8))) short short8;    // 8 bf16 (4 VGPRs)
typedef __attribute__((ext_vector_type(4))) float f32x4;

// Workspace layout (byte offsets). Total 573568 B.
#define WS_ATHI_B 0u          // ushort Athi[64][64]   8192  (A-op layout: [t][s])
#define WS_ATLO_B 8192u       // ushort Atlo[64][64]   8192
#define WS_GPK_B  16384u      // uint   gpk[256][256]  262144 (hi<<16 | lo per elem)
#define WS_W2HI_B 278528u     // ushort W2hi[256][256] 131072
#define WS_W2LO_B 409600u     // ushort W2lo[256][256] 131072
#define WS_POOL_B 540672u     // float  pool[32][256]  32768
#define WS_CNT_B  573440u     // uint   cnt[32]        128   (per-b ticket)

#define HP 264    // H2 plane row stride in shorts (256 + 8 pad)

__device__ __forceinline__ float fast_tanh(float v) {
  float e = __expf(2.0f * v);
  return 1.0f - __fdividef(2.0f, e + 1.0f);
}

// Truncation-based bf16 split: v ~= hi + lo with |err| <= 2^-17 * |v|.
__device__ __forceinline__ uint_t split_pack(float v) {
  uint_t b  = __float_as_uint(v);
  uint_t hi = b & 0xffff0000u;
  float  r  = v - __uint_as_float(hi);
  uint_t lo = __float_as_uint(r) >> 16;
  return hi | lo;
}

// Pack hi/lo halves of two packed u32 into bf16 pair dwords via v_perm.
__device__ __forceinline__ uint_t perm_hi(uint_t p0, uint_t p1) {
  return __builtin_amdgcn_perm(p1, p0, 0x07060302u);
}
__device__ __forceinline__ uint_t perm_lo(uint_t p0, uint_t p1) {
  return __builtin_amdgcn_perm(p1, p0, 0x05040100u);
}

union u4s8 { uint_t u[4]; short8 v; };

// ---------------------------------------------------------------------------
// Prep grid (1090 blocks):
//  blk 0          : attention matrix -> split bf16 planes Athi/Atlo ([t][s])
//  blk 1          : zero pool accumulator + per-b tickets
//  blk 2..1025    : g = emb @ W1^T (coalesced W1 reads, LDS partial reduce)
//  blk 1026..1089 : W2 -> split planes W2hi/W2lo, 4 c-rows per block
// ---------------------------------------------------------------------------
__global__ __launch_bounds__(256) void prep_kernel(
    const float* __restrict__ emb, const float* __restrict__ W1,
    const float* __restrict__ W2, char* __restrict__ ws)
{
  const int blk = blockIdx.x;
  const int tid = threadIdx.x;
  ushort_t* Athi = (ushort_t*)(ws + WS_ATHI_B);
  ushort_t* Atlo = (ushort_t*)(ws + WS_ATLO_B);
  uint_t*   gpk  = (uint_t*)  (ws + WS_GPK_B);
  ushort_t* W2hi = (ushort_t*)(ws + WS_W2HI_B);
  ushort_t* W2lo = (ushort_t*)(ws + WS_W2LO_B);
  float*    pool = (float*)   (ws + WS_POOL_B);
  uint_t*   cnt  = (uint_t*)  (ws + WS_CNT_B);

  if (blk == 0) {
    if (tid < WIN) {
      const int s = tid;
      const float omega = 60.0f * 2.0f * 3.14159265358979323846f / 4095.0f;
      float row[WIN];
      float sum = 0.0f;
      for (int t = 0; t < WIN; ++t) {
        float e = expf(cosf(omega * (float)(s - t)));
        row[t] = e;
        sum += e;
      }
      const float inv = 1.0f / sum;
      for (int t = 0; t < WIN; ++t) {
        uint_t pk = split_pack(row[t] * inv);
        Athi[t * WIN + s] = (ushort_t)(pk >> 16);
        Atlo[t * WIN + s] = (ushort_t)(pk & 0xffffu);
      }
    }
  } else if (blk == 1) {
    for (int i = tid; i < BB * DD; i += 256) pool[i] = 0.0f;
    if (tid < BB) cnt[tid] = 0u;
  } else if (blk < 1026) {
    const int gv = blk - 2;            // 0..1023
    const int d0 = (gv & 15) * 16;     // 16 d-columns
    const int v0 = (gv >> 4) * 4;      // 4 v-rows
    __shared__ float er[4 * DD];       // 4 KB
    __shared__ float ps[4][16][17];    // padded partials
    *(float4*)(er + tid * 4) = *(const float4*)(emb + v0 * DD + tid * 4);
    __syncthreads();
    const int kq = tid & 15;           // k-strip: [16kq, 16kq+16)
    const int dl = tid >> 4;           // 0..15
    const int d  = d0 + dl;
    float4 wv[4];
    #pragma unroll
    for (int j = 0; j < 4; ++j)
      wv[j] = *(const float4*)(W1 + d * DD + 16 * kq + 4 * j);  // coalesced
    #pragma unroll
    for (int v = 0; v < 4; ++v) {
      float a = 0.0f;
      #pragma unroll
      for (int j = 0; j < 4; ++j) {
        float4 e = *(const float4*)(er + v * DD + 16 * kq + 4 * j);
        a += e.x * wv[j].x + e.y * wv[j].y + e.z * wv[j].z + e.w * wv[j].w;
      }
      ps[v][dl][kq] = a;
    }
    __syncthreads();
    if (tid < 64) {
      const int v = tid >> 4, dr = tid & 15;
      float s = 0.0f;
      #pragma unroll
      for (int k = 0; k < 16; ++k) s += ps[v][dr][k];
      gpk[(v0 + v) * DD + d0 + dr] = split_pack(s);
    }
  } else {
    const int c0 = (blk - 1026) * 4;
    #pragma unroll
    for (int i = 0; i < 4; ++i) {
      const int c = c0 + i;
      uint_t pk = split_pack(W2[c * DD + tid]);
      W2hi[c * DD + tid] = (ushort_t)(pk >> 16);
      W2lo[c * DD + tid] = (ushort_t)(pk & 0xffffu);
    }
  }
}

// ---------------------------------------------------------------------------
// Main fused kernel: one block (512 thr, 8 waves) per (batch b, window n).
// EXACT R8 hot path (proven 122 us: spread pool atomics, padded hi/lo planes,
// shfl gather, W2 double-buffer). New: per-b ticket finisher — the 64th
// block of each b computes out[b] = bc + pool[b]·Wc^T / S with coherent
// atomic-loads, replacing the separate final kernel (one fewer launch).
// Ticket atomics: 64 per b over 32 addresses — R10-proven-benign scale.
// ---------------------------------------------------------------------------
__global__ __launch_bounds__(512, 4) void main_kernel(
    const int*      __restrict__ x,    const uint_t* __restrict__ gpk,
    const ushort_t* __restrict__ Athi, const ushort_t* __restrict__ Atlo,
    const float*    __restrict__ b1,
    const ushort_t* __restrict__ W2hi, const ushort_t* __restrict__ W2lo,
    const float*    __restrict__ b2,   const float* __restrict__ Wc,
    const float*    __restrict__ bc,
    float* __restrict__ pool, uint_t* __restrict__ cnt,
    float* __restrict__ out)
{
  __shared__ ushort_t Hhi[WIN][HP];   // 33792 B
  __shared__ ushort_t Hlo[WIN][HP];   // 33792 B (total 67584 -> 2 blocks/CU)
  __shared__ int okflag;
  __shared__ float parts[4][2];

  const int tid  = threadIdx.x;
  const int lane = tid & 63;
  const int w    = tid >> 6;       // 0..7
  const int quad = lane >> 4;
  const int l16  = lane & 15;
  const int b = blockIdx.x >> 6;
  const int n = blockIdx.x & 63;

  const int dbase = 32 * w;        // this wave's d-slice (P2) == c-slice (P4)
  const int cbase = dbase;

  // --- P1: gather (single x load + shfl broadcast) ---
  const int xv = x[b * SS + n * WIN + lane];
  uint_t q[2][2][8];
  #pragma unroll
  for (int k0 = 0; k0 < 2; ++k0) {
    const int sl = k0 * 32 + quad * 8;
    int xs[8];
    #pragma unroll
    for (int j = 0; j < 8; ++j) xs[j] = __shfl(xv, sl + j, 64);
    #pragma unroll
    for (int nt = 0; nt < 2; ++nt) {
      const int d = dbase + 16 * nt + l16;
      #pragma unroll
      for (int j = 0; j < 8; ++j) q[k0][nt][j] = gpk[xs[j] * DD + d];
    }
  }

  float b1v[2], b2v[2];
  #pragma unroll
  for (int nt = 0; nt < 2; ++nt) {
    b1v[nt] = b1[dbase + 16 * nt + l16];
    b2v[nt] = b2[cbase + 16 * nt + l16];
  }

  // --- P2: attention MFMA ---
  f32x4 acc1[4][2];
  #pragma unroll
  for (int mt = 0; mt < 4; ++mt)
    #pragma unroll
    for (int nt = 0; nt < 2; ++nt) acc1[mt][nt] = (f32x4)0.0f;

  #pragma unroll
  for (int k0 = 0; k0 < 2; ++k0) {
    const int sl = k0 * 32 + quad * 8;
    short8 bh[2], bl[2];
    #pragma unroll
    for (int nt = 0; nt < 2; ++nt) {
      u4s8 h, l;
      #pragma unroll
      for (int p = 0; p < 4; ++p) {
        h.u[p] = perm_hi(q[k0][nt][2 * p], q[k0][nt][2 * p + 1]);
        l.u[p] = perm_lo(q[k0][nt][2 * p], q[k0][nt][2 * p + 1]);
      }
      bh[nt] = h.v;
      bl[nt] = l.v;
    }
    #pragma unroll
    for (int mt = 0; mt < 4; ++mt) {
      const int t = mt * 16 + l16;
      short8 ah = *(const short8*)(Athi + t * WIN + sl);   // L1/L2-resident
      short8 al = *(const short8*)(Atlo + t * WIN + sl);
      #pragma unroll
      for (int nt = 0; nt < 2; ++nt) {
        acc1[mt][nt] = __builtin_amdgcn_mfma_f32_16x16x32_bf16(ah, bh[nt], acc1[mt][nt], 0, 0, 0);
        acc1[mt][nt] = __builtin_amdgcn_mfma_f32_16x16x32_bf16(ah, bl[nt], acc1[mt][nt], 0, 0, 0);
        acc1[mt][nt] = __builtin_amdgcn_mfma_f32_16x16x32_bf16(al, bh[nt], acc1[mt][nt], 0, 0, 0);
      }
    }
  }

  // --- P3: tanh(+b1), split, store to hi/lo planes ---
  #pragma unroll
  for (int nt = 0; nt < 2; ++nt) {
    const int d = dbase + 16 * nt + l16;
    #pragma unroll
    for (int mt = 0; mt < 4; ++mt)
      #pragma unroll
      for (int r = 0; r < 4; ++r) {
        const int t = mt * 16 + quad * 4 + r;
        float h = fast_tanh(acc1[mt][nt][r] + b1v[nt]);
        uint_t pk = split_pack(h);
        Hhi[t][d] = (ushort_t)(pk >> 16);
        Hlo[t][d] = (ushort_t)(pk & 0xffffu);
      }
  }
  __syncthreads();

  // --- P4: matmul2 MFMA, W2 double-buffered, A-frags direct b128 ---
  f32x4 acc2[4][2];
  #pragma unroll
  for (int mt = 0; mt < 4; ++mt)
    #pragma unroll
    for (int nt = 0; nt < 2; ++nt) acc2[mt][nt] = (f32x4)0.0f;

  short8 wh[2][2], wl[2][2];
  {
    const int dsl0 = quad * 8;
    #pragma unroll
    for (int nt = 0; nt < 2; ++nt) {
      const int c = cbase + 16 * nt + l16;
      wh[0][nt] = *(const short8*)(W2hi + c * DD + dsl0);
      wl[0][nt] = *(const short8*)(W2lo + c * DD + dsl0);
    }
  }

  #pragma unroll 2
  for (int k0 = 0; k0 < 8; ++k0) {
    const int cur = k0 & 1, nxt = cur ^ 1;
    const int dsl = k0 * 32 + quad * 8;
    if (k0 < 7) {
      const int dsln = dsl + 32;
      #pragma unroll
      for (int nt = 0; nt < 2; ++nt) {
        const int c = cbase + 16 * nt + l16;
        wh[nxt][nt] = *(const short8*)(W2hi + c * DD + dsln);   // prefetch k0+1
        wl[nxt][nt] = *(const short8*)(W2lo + c * DD + dsln);
      }
    }
    #pragma unroll
    for (int mt = 0; mt < 4; ++mt) {
      const int t = mt * 16 + l16;
      short8 ah = *(const short8*)(&Hhi[t][dsl]);   // ds_read_b128, clean
      short8 al = *(const short8*)(&Hlo[t][dsl]);
      #pragma unroll
      for (int nt = 0; nt < 2; ++nt) {
        acc2[mt][nt] = __builtin_amdgcn_mfma_f32_16x16x32_bf16(ah, wh[cur][nt], acc2[mt][nt], 0, 0, 0);
        acc2[mt][nt] = __builtin_amdgcn_mfma_f32_16x16x32_bf16(ah, wl[cur][nt], acc2[mt][nt], 0, 0, 0);
        acc2[mt][nt] = __builtin_amdgcn_mfma_f32_16x16x32_bf16(al, wh[cur][nt], acc2[mt][nt], 0, 0, 0);
      }
    }
  }

  // --- P5: tanh(+b2) + token-sum, spread atomics into pool (R8-proven) ---
  #pragma unroll
  for (int nt = 0; nt < 2; ++nt) {
    float p = 0.0f;
    #pragma unroll
    for (int mt = 0; mt < 4; ++mt)
      #pragma unroll
      for (int r = 0; r < 4; ++r)
        p += fast_tanh(acc2[mt][nt][r] + b2v[nt]);
    p += __shfl_xor(p, 16, 64);
    p += __shfl_xor(p, 32, 64);
    if (quad == 0) atomicAdd(&pool[b * DD + cbase + 16 * nt + l16], p);
  }

  // --- Ticket: last block of this b computes the head ---
  __syncthreads();                  // all waves' pool atomics drained (vmcnt 0)
  if (tid == 0) {
    __threadfence();                // order pool atomics before ticket
    uint_t old = atomicAdd(&cnt[b], 1u);
    okflag = (old == (uint_t)(NW - 1)) ? 1 : 0;
  }
  __syncthreads();

  if (okflag) {
    if (tid < DD) {
      float v = atomicAdd(&pool[b * DD + tid], 0.0f);   // coherent load
      float s0 = v * Wc[tid];
      float s1 = v * Wc[DD + tid];
      #pragma unroll
      for (int off = 1; off < 64; off <<= 1) {
        s0 += __shfl_xor(s0, off, 64);
        s1 += __shfl_xor(s1, off, 64);
      }
      if (lane == 0) { parts[w][0] = s0; parts[w][1] = s1; }
    }
    __syncthreads();
    if (tid == 0) {
      float s0 = parts[0][0] + parts[1][0] + parts[2][0] + parts[3][0];
      float s1 = parts[0][1] + parts[1][1] + parts[2][1] + parts[3][1];
      out[b * CC + 0] = s0 * (1.0f / SS) + bc[0];
      out[b * CC + 1] = s1 * (1.0f / SS) + bc[1];
    }
  }
}

extern "C" void kernel_launch(void* const* d_in, const int* in_sizes, int n_in,
                              void* d_out, int out_size, void* d_ws, size_t ws_size,
                              hipStream_t stream) {
  const int*   x   = (const int*)  d_in[0];
  const float* emb = (const float*)d_in[1];
  const float* W1  = (const float*)d_in[2];
  const float* b1  = (const float*)d_in[3];
  const float* W2  = (const float*)d_in[4];
  const float* b2  = (const float*)d_in[5];
  const float* Wc  = (const float*)d_in[6];
  const float* bc  = (const float*)d_in[7];
  float* out = (float*)d_out;
  char*  ws  = (char*)d_ws;

  prep_kernel<<<1090, 256, 0, stream>>>(emb, W1, W2, ws);
  main_kernel<<<BB * NW, 512, 0, stream>>>(
      x,
      (const uint_t*)  (ws + WS_GPK_B),
      (const ushort_t*)(ws + WS_ATHI_B), (const ushort_t*)(ws + WS_ATLO_B),
      b1,
      (const ushort_t*)(ws + WS_W2HI_B), (const ushort_t*)(ws + WS_W2LO_B),
      b2, Wc, bc,
      (float*)(ws + WS_POOL_B), (uint_t*)(ws + WS_CNT_B),
      out);
}